// Round 7
// baseline (267.774 us; speedup 1.0000x reference)
//
#include <hip/hip_runtime.h>

constexpr int Bb = 4;
constexpr int Ss = 2048;
constexpr int QSTR = 1536;   // combined qkv row stride (g 0..767, t 768..1535)

typedef __bf16 bf16x8 __attribute__((ext_vector_type(8)));
typedef __bf16 bf16x4 __attribute__((ext_vector_type(4)));
typedef float  f32x4  __attribute__((ext_vector_type(4)));

// async global->LDS, 16B per lane; dest = wave-uniform base + lane*16
__device__ __forceinline__ void glds16(const void* g, void* l) {
    __builtin_amdgcn_global_load_lds(
        (const __attribute__((address_space(1))) unsigned int*)g,
        (__attribute__((address_space(3))) unsigned int*)l, 16, 0, 0);
}

// ---------------------------------------------------------------------------
// convert_all: fp32 -> bf16 for x and 5 weight matrices (7 entries).
// ---------------------------------------------------------------------------
struct CvtArgs {
    const float* src[9];
    __bf16* dst[9];
    int start[10];
};

__global__ __launch_bounds__(256) void convert_all(CvtArgs a)
{
    int e = 0;
    const int bid = blockIdx.x;
#pragma unroll
    for (int i = 0; i < 8; i++) if (bid >= a.start[i + 1]) e = i + 1;
    const int idx = (bid - a.start[e]) * 256 + threadIdx.x;
    const float* s = a.src[e];
    float4 v0 = *(const float4*)&s[(size_t)idx * 8];
    float4 v1 = *(const float4*)&s[(size_t)idx * 8 + 4];
    bf16x8 o;
    o[0] = (__bf16)v0.x; o[1] = (__bf16)v0.y; o[2] = (__bf16)v0.z; o[3] = (__bf16)v0.w;
    o[4] = (__bf16)v1.x; o[5] = (__bf16)v1.y; o[6] = (__bf16)v1.z; o[7] = (__bf16)v1.w;
    *(bf16x8*)&a.dst[e][(size_t)idx * 8] = o;
}

// ---------------------------------------------------------------------------
// build_wcomb: block-diagonal merged out-proj weight [512 x 512] bf16.
// row n<256: cols 0-255 = g_out_w[n], else 0. row n>=256: cols 256-511 =
// t_out_w[n-256], else 0. 128 blocks x 256 thr x 8 elems.
// ---------------------------------------------------------------------------
__global__ __launch_bounds__(256) void build_wcomb(
    const float* __restrict__ g, const float* __restrict__ t,
    __bf16* __restrict__ w)
{
    const int idx = blockIdx.x * 256 + threadIdx.x;   // 0..32767
    const int row = idx >> 6, grp = idx & 63;         // cols grp*8..+7
    bf16x8 o;
    const bool diag = (row < 256) == (grp < 32);
    if (diag) {
        const float* s = (row < 256) ? &g[(size_t)row * 256 + grp * 8]
                                     : &t[(size_t)(row - 256) * 256 + (grp - 32) * 8];
        float4 v0 = *(const float4*)s;
        float4 v1 = *(const float4*)(s + 4);
        o[0] = (__bf16)v0.x; o[1] = (__bf16)v0.y; o[2] = (__bf16)v0.z; o[3] = (__bf16)v0.w;
        o[4] = (__bf16)v1.x; o[5] = (__bf16)v1.y; o[6] = (__bf16)v1.z; o[7] = (__bf16)v1.w;
    } else {
#pragma unroll
        for (int i = 0; i < 8; i++) o[i] = (__bf16)0.f;
    }
    *(bf16x8*)&w[(size_t)idx * 8] = o;
}

// ---------------------------------------------------------------------------
// gemm128: BM=BN=128, BK=64; 4 waves each 64x64 (4x4 MFMA accs).
// 32 MFMAs per wave per K-iter between barriers. For the big QKV GEMM.
// XOR swizzle: LDS slot (row,g) holds global chunk (row, g^(row&7)).
// ---------------------------------------------------------------------------
__global__ __launch_bounds__(256) void gemm128(
    const __bf16* __restrict__ A, const __bf16* __restrict__ W,
    const float* __restrict__ bias, const float* __restrict__ bias2, int bsplit,
    __bf16* __restrict__ C, int K, int ldc)
{
    __shared__ __bf16 As[128 * 64];
    __shared__ __bf16 Ws[128 * 64];
    const int tid = threadIdx.x;
    const int lane = tid & 63;
    const int wv = tid >> 6;
    const int wm = (wv >> 1) * 64;
    const int wn = (wv & 1) * 64;
    const int qrow = lane & 15;
    const int quad = lane >> 4;
    const int n0 = blockIdx.x * 128;
    const int m0 = blockIdx.y * 128;

    f32x4 acc[4][4];
#pragma unroll
    for (int i = 0; i < 4; i++)
#pragma unroll
        for (int j = 0; j < 4; j++) acc[i][j] = {0.f, 0.f, 0.f, 0.f};

    for (int k0 = 0; k0 < K; k0 += 64) {
        __syncthreads();
        // 1024 chunks per matrix (128 rows x 8); 4 glds calls per wave each
#pragma unroll
        for (int i = 0; i < 4; i++) {
            const int c = (wv * 4 + i) * 64 + lane;
            const int row = c >> 3, g = c & 7;
            const int gs = (g ^ (row & 7)) * 8;
            glds16(&A[(size_t)(m0 + row) * K + k0 + gs], &As[(wv * 4 + i) * 512]);
            glds16(&W[(size_t)(n0 + row) * K + k0 + gs], &Ws[(wv * 4 + i) * 512]);
        }
        __syncthreads();
#pragma unroll
        for (int ksub = 0; ksub < 2; ksub++) {
            const int gl = ksub * 4 + quad;
            bf16x8 af[4], bf[4];
#pragma unroll
            for (int mi = 0; mi < 4; mi++) {
                const int row = wm + mi * 16 + qrow;
                af[mi] = *(const bf16x8*)&As[row * 64 + (gl ^ (row & 7)) * 8];
            }
#pragma unroll
            for (int ni = 0; ni < 4; ni++) {
                const int row = wn + ni * 16 + qrow;
                bf[ni] = *(const bf16x8*)&Ws[row * 64 + (gl ^ (row & 7)) * 8];
            }
#pragma unroll
            for (int mi = 0; mi < 4; mi++)
#pragma unroll
                for (int ni = 0; ni < 4; ni++)
                    acc[mi][ni] = __builtin_amdgcn_mfma_f32_16x16x32_bf16(
                        af[mi], bf[ni], acc[mi][ni], 0, 0, 0);
        }
    }

    float bz[4];
#pragma unroll
    for (int ni = 0; ni < 4; ni++) {
        const int n = n0 + wn + ni * 16 + qrow;
        bz[ni] = (n < bsplit) ? bias[n] : bias2[n - bsplit];
    }
#pragma unroll
    for (int mi = 0; mi < 4; mi++)
#pragma unroll
        for (int r = 0; r < 4; r++) {
            const int row = m0 + wm + mi * 16 + quad * 4 + r;
#pragma unroll
            for (int ni = 0; ni < 4; ni++) {
                float v = acc[mi][ni][r] + bz[ni];
                C[(size_t)row * ldc + n0 + wn + ni * 16 + qrow] = (__bf16)v;
            }
        }
}

// ---------------------------------------------------------------------------
// gemm64: BM=BN=64, BK=128; 4 waves each 32x32 (2x2 accs), 16 MFMAs/iter.
// Two 8-chunk halves, each with the XOR swizzle. For the N=256/512 GEMMs.
// ---------------------------------------------------------------------------
template<bool SILU, bool OUT_BF16>
__global__ __launch_bounds__(256) void gemm64(
    const __bf16* __restrict__ A, const __bf16* __restrict__ W,
    const float* __restrict__ bias, const float* __restrict__ bias2, int bsplit,
    void* __restrict__ C, int K, int ldc)
{
    __shared__ __bf16 As[64 * 128];
    __shared__ __bf16 Ws[64 * 128];
    const int tid = threadIdx.x;
    const int lane = tid & 63;
    const int wv = tid >> 6;
    const int wm = (wv >> 1) * 32;
    const int wn = (wv & 1) * 32;
    const int qrow = lane & 15;
    const int quad = lane >> 4;
    const int n0 = blockIdx.x * 64;
    const int m0 = blockIdx.y * 64;

    f32x4 acc[2][2];
#pragma unroll
    for (int i = 0; i < 2; i++)
#pragma unroll
        for (int j = 0; j < 2; j++) acc[i][j] = {0.f, 0.f, 0.f, 0.f};

    for (int k0 = 0; k0 < K; k0 += 128) {
        __syncthreads();
        // 1024 chunks per matrix (64 rows x 16 slots); 4 glds calls per wave
#pragma unroll
        for (int i = 0; i < 4; i++) {
            const int c = (wv * 4 + i) * 64 + lane;
            const int row = c >> 4, s = c & 15;
            const int gs = ((s & 8) | ((s ^ row) & 7)) * 8;
            glds16(&A[(size_t)(m0 + row) * K + k0 + gs], &As[(wv * 4 + i) * 512]);
            glds16(&W[(size_t)(n0 + row) * K + k0 + gs], &Ws[(wv * 4 + i) * 512]);
        }
        __syncthreads();
#pragma unroll
        for (int ksub = 0; ksub < 4; ksub++) {
            const int gl = ksub * 4 + quad;
            bf16x8 af[2], bf[2];
#pragma unroll
            for (int mi = 0; mi < 2; mi++) {
                const int row = wm + mi * 16 + qrow;
                const int s = (gl & 8) | ((gl ^ row) & 7);
                af[mi] = *(const bf16x8*)&As[row * 128 + s * 8];
            }
#pragma unroll
            for (int ni = 0; ni < 2; ni++) {
                const int row = wn + ni * 16 + qrow;
                const int s = (gl & 8) | ((gl ^ row) & 7);
                bf[ni] = *(const bf16x8*)&Ws[row * 128 + s * 8];
            }
#pragma unroll
            for (int mi = 0; mi < 2; mi++)
#pragma unroll
                for (int ni = 0; ni < 2; ni++)
                    acc[mi][ni] = __builtin_amdgcn_mfma_f32_16x16x32_bf16(
                        af[mi], bf[ni], acc[mi][ni], 0, 0, 0);
        }
    }

    float bz[2];
#pragma unroll
    for (int ni = 0; ni < 2; ni++) {
        const int n = n0 + wn + ni * 16 + qrow;
        bz[ni] = (n < bsplit) ? bias[n] : bias2[n - bsplit];
    }
#pragma unroll
    for (int mi = 0; mi < 2; mi++)
#pragma unroll
        for (int r = 0; r < 4; r++) {
            const int row = m0 + wm + mi * 16 + quad * 4 + r;
#pragma unroll
            for (int ni = 0; ni < 2; ni++) {
                float v = acc[mi][ni][r] + bz[ni];
                if (SILU) v = v / (1.f + __expf(-v));
                const int col = n0 + wn + ni * 16 + qrow;
                if (OUT_BF16)
                    ((__bf16*)C)[(size_t)row * ldc + col] = (__bf16)v;
                else
                    ((float*)C)[(size_t)row * ldc + col] = v;
            }
        }
}

// ---------------------------------------------------------------------------
// Global MHA split-K x4 partials. No-max softmax (scores O(0.3)); l via MFMA
// against all-ones B. Grid 4096 = (b:4, h:8, qc:32, sp:4); 4 waves x 16 q.
// ---------------------------------------------------------------------------
__global__ __launch_bounds__(256) void attn_global_part(
    const __bf16* __restrict__ qkv, float* __restrict__ Op, float* __restrict__ Lp)
{
    __shared__ __bf16 Kl[64 * 32];
    __shared__ __bf16 Vt[32 * 72];
    __shared__ __bf16 Pl[4][16 * 72];

    const int t = threadIdx.x;
    const int bid = blockIdx.x;
    const int sp = bid & 3;
    const int qc = (bid >> 2) & 31;
    const int h  = (bid >> 7) & 7;
    const int b  = bid >> 10;
    const int bS = b * Ss;
    const int q0 = qc * 64;

    const int lane = t & 63;
    const int wv = t >> 6;
    const int qrow = lane & 15;
    const int quad = lane >> 4;
    const float cQ = 1.4426950408889634f * 0.17677669529663687f; // log2e/sqrt(32)

    bf16x8 qf;
    {
        bf16x8 qraw = *(const bf16x8*)(qkv +
            (size_t)(bS + q0 + wv * 16 + qrow) * QSTR + h * 32 + quad * 8);
#pragma unroll
        for (int i = 0; i < 8; i++) qf[i] = (__bf16)((float)qraw[i] * cQ);
    }
    bf16x8 ones;
#pragma unroll
    for (int i = 0; i < 8; i++) ones[i] = (__bf16)1.0f;

    f32x4 o0 = {0.f, 0.f, 0.f, 0.f};
    f32x4 o1 = {0.f, 0.f, 0.f, 0.f};
    f32x4 lac = {0.f, 0.f, 0.f, 0.f};
    const f32x4 z = {0.f, 0.f, 0.f, 0.f};

    const int vkey = t & 63, vdg = t >> 6;
    const int kc_c = wv * 64 + lane;
    const int kkey = kc_c >> 2, kdg = kc_c & 3;

    for (int kc = sp * 8; kc < sp * 8 + 8; kc++) {
        __syncthreads();
        glds16(qkv + (size_t)(bS + kc * 64 + kkey) * QSTR + 256 + h * 32 + kdg * 8,
               &Kl[wv * 512]);
        {
            const __bf16* src = qkv + (size_t)(bS + kc * 64 + vkey) * QSTR + 512 + h * 32 + vdg * 8;
            bf16x8 v = *(const bf16x8*)src;
#pragma unroll
            for (int i = 0; i < 8; i++) Vt[(vdg * 8 + i) * 72 + vkey] = v[i];
        }
        __syncthreads();

        f32x4 s[4];
#pragma unroll
        for (int kg = 0; kg < 4; kg++) {
            bf16x8 kf = *(const bf16x8*)&Kl[(kg * 16 + qrow) * 32 + quad * 8];
            s[kg] = __builtin_amdgcn_mfma_f32_16x16x32_bf16(qf, kf, z, 0, 0, 0);
        }
#pragma unroll
        for (int kg = 0; kg < 4; kg++) {
            float p0 = exp2f(s[kg][0]);
            float p1 = exp2f(s[kg][1]);
            float p2 = exp2f(s[kg][2]);
            float p3 = exp2f(s[kg][3]);
            __bf16* pw = &Pl[wv][kg * 16 + qrow];
            pw[(quad * 4 + 0) * 72] = (__bf16)p0;
            pw[(quad * 4 + 1) * 72] = (__bf16)p1;
            pw[(quad * 4 + 2) * 72] = (__bf16)p2;
            pw[(quad * 4 + 3) * 72] = (__bf16)p3;
        }
        bf16x8 pf0 = *(const bf16x8*)&Pl[wv][qrow * 72 + quad * 8];
        bf16x8 pf1 = *(const bf16x8*)&Pl[wv][qrow * 72 + 32 + quad * 8];
        bf16x8 vf00 = *(const bf16x8*)&Vt[qrow * 72 + quad * 8];
        bf16x8 vf01 = *(const bf16x8*)&Vt[qrow * 72 + 32 + quad * 8];
        bf16x8 vf10 = *(const bf16x8*)&Vt[(16 + qrow) * 72 + quad * 8];
        bf16x8 vf11 = *(const bf16x8*)&Vt[(16 + qrow) * 72 + 32 + quad * 8];
        o0 = __builtin_amdgcn_mfma_f32_16x16x32_bf16(pf0, vf00, o0, 0, 0, 0);
        o1 = __builtin_amdgcn_mfma_f32_16x16x32_bf16(pf0, vf10, o1, 0, 0, 0);
        lac = __builtin_amdgcn_mfma_f32_16x16x32_bf16(pf0, ones, lac, 0, 0, 0);
        o0 = __builtin_amdgcn_mfma_f32_16x16x32_bf16(pf1, vf01, o0, 0, 0, 0);
        o1 = __builtin_amdgcn_mfma_f32_16x16x32_bf16(pf1, vf11, o1, 0, 0, 0);
        lac = __builtin_amdgcn_mfma_f32_16x16x32_bf16(pf1, ones, lac, 0, 0, 0);
    }

#pragma unroll
    for (int r = 0; r < 4; r++) {
        const int row = q0 + wv * 16 + quad * 4 + r;
        const int gid = (b * 8 + h) * 2048 + row;
        float* po = Op + (size_t)sp * 2097152 + (size_t)gid * 32;
        po[qrow]      = o0[r];
        po[16 + qrow] = o1[r];
        if (qrow == 0) Lp[sp * 65536 + gid] = lac[r];
    }
}

// ---------------------------------------------------------------------------
// Combine 4 split partials -> acat bf16 [B,S,512] cols 0-255.
// ---------------------------------------------------------------------------
__global__ __launch_bounds__(256) void attn_combine(
    const float* __restrict__ Op, const float* __restrict__ Lp,
    __bf16* __restrict__ acat)
{
    const int t = blockIdx.x * 256 + threadIdx.x;   // 0 .. 524287
    const int gid = t >> 3;
    const int dg = t & 7;
    const int b = gid >> 14;
    const int h = (gid >> 11) & 7;
    const int q = gid & 2047;

    const float li = 1.f / (Lp[gid] + Lp[65536 + gid] + Lp[131072 + gid] + Lp[196608 + gid]);
    float4 a0 = *(const float4*)&Op[(size_t)gid * 32 + dg * 4];
    float4 a1 = *(const float4*)&Op[2097152 + (size_t)gid * 32 + dg * 4];
    float4 a2 = *(const float4*)&Op[4194304 + (size_t)gid * 32 + dg * 4];
    float4 a3 = *(const float4*)&Op[6291456 + (size_t)gid * 32 + dg * 4];
    bf16x4 r;
    r[0] = (__bf16)((a0.x + a1.x + a2.x + a3.x) * li);
    r[1] = (__bf16)((a0.y + a1.y + a2.y + a3.y) * li);
    r[2] = (__bf16)((a0.z + a1.z + a2.z + a3.z) * li);
    r[3] = (__bf16)((a0.w + a1.w + a2.w + a3.w) * li);
    *(bf16x4*)&acat[(size_t)(b * Ss + q) * 512 + h * 32 + dg * 4] = r;
}

// ---------------------------------------------------------------------------
// Local windowed MHA -> acat cols 256-511. Wave per (b,s,h).
// ---------------------------------------------------------------------------
__global__ __launch_bounds__(256) void attn_local(
    const __bf16* __restrict__ qkv, __bf16* __restrict__ acat)
{
    const int lane = threadIdx.x & 63;
    const int w = blockIdx.x * 4 + (threadIdx.x >> 6);
    const int b = w >> 13;
    const int rem = w & 8191;
    const int s = rem >> 2;
    const int h = rem & 3;

    const float q = (float)qkv[(size_t)(b * Ss + s) * QSTR + 768 + h * 64 + lane];
    float sc[5], vv[5];
#pragma unroll
    for (int j = 0; j < 5; j++) {
        int pos = s + j - 2;
        bool valid = (pos >= 0) && (pos < Ss);
        int cpos = valid ? pos : 0;
        const size_t rb = (size_t)(b * Ss + cpos) * QSTR;
        float kj = valid ? (float)qkv[rb + 1024 + h * 64 + lane] : 0.f;
        vv[j] = valid ? (float)qkv[rb + 1280 + h * 64 + lane] : 0.f;
        float p = q * kj;
#pragma unroll
        for (int off = 32; off > 0; off >>= 1) p += __shfl_xor(p, off, 64);
        sc[j] = valid ? p * 0.125f : -1e30f;
    }
    float m = sc[0];
#pragma unroll
    for (int j = 1; j < 5; j++) m = fmaxf(m, sc[j]);
    float l = 0.f, o = 0.f;
#pragma unroll
    for (int j = 0; j < 5; j++) {
        float p = __expf(sc[j] - m);
        l += p; o += p * vv[j];
    }
    acat[(size_t)(b * Ss + s) * 512 + 256 + h * 64 + lane] = (__bf16)(o / l);
}

// ---------------------------------------------------------------------------
// out = LayerNorm(a + r) * g + be over last dim (256). Wave per token.
// ---------------------------------------------------------------------------
__global__ __launch_bounds__(256) void ln_residual(
    const float* __restrict__ a, const float* __restrict__ r,
    const float* __restrict__ g, const float* __restrict__ be,
    float* __restrict__ out, __bf16* __restrict__ ob)
{
    const int lane = threadIdx.x & 63;
    const int tok = blockIdx.x * 4 + (threadIdx.x >> 6);
    float4 xa = ((const float4*)a)[(size_t)tok * 64 + lane];
    float4 xr = ((const float4*)r)[(size_t)tok * 64 + lane];
    float4 x;
    x.x = xa.x + xr.x; x.y = xa.y + xr.y; x.z = xa.z + xr.z; x.w = xa.w + xr.w;
    float sum = x.x + x.y + x.z + x.w;
#pragma unroll
    for (int off = 32; off > 0; off >>= 1) sum += __shfl_xor(sum, off, 64);
    float mu = sum * (1.f / 256.f);
    float4 c;
    c.x = x.x - mu; c.y = x.y - mu; c.z = x.z - mu; c.w = x.w - mu;
    float sq = c.x * c.x + c.y * c.y + c.z * c.z + c.w * c.w;
#pragma unroll
    for (int off = 32; off > 0; off >>= 1) sq += __shfl_xor(sq, off, 64);
    float rs = rsqrtf(sq * (1.f / 256.f) + 1e-5f);
    float4 gg = ((const float4*)g)[lane];
    float4 bb = ((const float4*)be)[lane];
    float4 o;
    o.x = c.x * rs * gg.x + bb.x; o.y = c.y * rs * gg.y + bb.y;
    o.z = c.z * rs * gg.z + bb.z; o.w = c.w * rs * gg.w + bb.w;
    ((float4*)out)[(size_t)tok * 64 + lane] = o;
    if (ob) {
        bf16x4 hh;
        hh[0] = (__bf16)o.x; hh[1] = (__bf16)o.y; hh[2] = (__bf16)o.z; hh[3] = (__bf16)o.w;
        *(bf16x4*)&ob[(size_t)tok * 256 + lane * 4] = hh;
    }
}

// ---------------------------------------------------------------------------
extern "C" void kernel_launch(void* const* d_in, const int* in_sizes, int n_in,
                              void* d_out, int out_size, void* d_ws, size_t ws_size,
                              hipStream_t stream)
{
    const float* x      = (const float*)d_in[0];
    const float* g_in_w = (const float*)d_in[1];
    const float* g_in_b = (const float*)d_in[2];
    const float* g_out_w= (const float*)d_in[3];
    const float* g_out_b= (const float*)d_in[4];
    const float* t_in_w = (const float*)d_in[5];
    const float* t_in_b = (const float*)d_in[6];
    const float* t_out_w= (const float*)d_in[7];
    const float* t_out_b= (const float*)d_in[8];
    const float* fus_w1 = (const float*)d_in[9];
    const float* fus_b1 = (const float*)d_in[10];
    const float* fus_w2 = (const float*)d_in[11];
    const float* fus_b2 = (const float*)d_in[12];
    const float* ffn_w1 = (const float*)d_in[13];
    const float* ffn_b1 = (const float*)d_in[14];
    const float* ffn_w2 = (const float*)d_in[15];
    const float* ffn_b2 = (const float*)d_in[16];
    const float* gn_g   = (const float*)d_in[17];
    const float* gn_b   = (const float*)d_in[18];
    const float* fn_g   = (const float*)d_in[19];
    const float* fn_b   = (const float*)d_in[20];
    float* out = (float*)d_out;
    float* ws  = (float*)d_ws;

    // ws layout in f32 slots (peak 19,529,728 slots = 78.1 MB; 84 MB known-safe)
    __bf16* xb     = (__bf16*)(ws);                 // [0, 1048576)
    __bf16* wb     = (__bf16*)(ws + 1048576);       // [1048576, 1572864)
    __bf16* wcomb  = (__bf16*)(ws + 1572864);       // [1572864, 1703936) 512x512
    __bf16* qkvgl  = (__bf16*)(ws + 1703936);       // [1703936, 7995392)  8192x1536
    __bf16* acat   = (__bf16*)(ws + 7995392);       // [7995392, 10092544) 8192x512
    __bf16* fcomb  = (__bf16*)(ws + 10092544);      // [10092544, 12189696) 8192x512
    __bf16* h1     = (__bf16*)(ws + 12189696);      // [12189696, 14286848) 8192x512
    float*  xf     = ws + 14286848;                 // [14286848, 16384000) fp32
    float*  x2     = ws + 16384000;                 // [16384000, 18481152) fp32
    __bf16* x2b    = (__bf16*)(ws + 18481152);      // [18481152, 19529728)
    __bf16* h2     = h1;                            // reuse
    float*  xff    = xf;                            // reuse
    // attention partials: live only between part and combine; overlap
    // fcomb+h1+xf+x2 (all written later). Lp overlaps x2b.
    float* Op = ws + 10092544;                      // 4 x 65536 x 32 fp32 = 8388608
    float* Lp = ws + 18481152;                      // 4 x 65536 fp32

    __bf16* w_gin  = wb;              // [1536x256] combined (g rows 0-767, t 768-1535)
    __bf16* w_f1   = wb + 393216;     // bf16 offsets within wb (in bf16 units)
    __bf16* w_f2   = wb + 655360;
    __bf16* w_n1   = wb + 786432;
    __bf16* w_n2   = wb + 917504;

    CvtArgs ca;
    ca.src[0] = x;      ca.dst[0] = xb;
    ca.src[1] = g_in_w; ca.dst[1] = w_gin;
    ca.src[2] = t_in_w; ca.dst[2] = w_gin + 196608;
    ca.src[3] = fus_w1; ca.dst[3] = w_f1;
    ca.src[4] = fus_w2; ca.dst[4] = w_f2;
    ca.src[5] = ffn_w1; ca.dst[5] = w_n1;
    ca.src[6] = ffn_w2; ca.dst[6] = w_n2;
    ca.src[7] = x;      ca.dst[7] = xb;     // unused
    ca.src[8] = x;      ca.dst[8] = xb;     // unused
    int st[10] = {0, 1024, 1120, 1216, 1344, 1408, 1472, 1536, 1 << 30, 1 << 30};
    for (int i = 0; i < 10; i++) ca.start[i] = st[i];

    convert_all<<<dim3(1536), 256, 0, stream>>>(ca);
    build_wcomb<<<dim3(128), 256, 0, stream>>>(g_out_w, t_out_w, wcomb);

    const int BIG = 1 << 30;
    // Combined QKV projection: M=8192, N=1536, K=256 -> qkvgl (128x128 tiles)
    gemm128<<<dim3(12, 64), 256, 0, stream>>>(
        xb, w_gin, g_in_b, t_in_b, 768, qkvgl, 256, QSTR);
    attn_local<<<dim3(8192), 256, 0, stream>>>(qkvgl, acat);
    // Global attention: split-K x4 partials + combine -> acat cols 0-255
    attn_global_part<<<dim3(4096), 256, 0, stream>>>(qkvgl, Op, Lp);
    attn_combine<<<dim3(2048), 256, 0, stream>>>(Op, Lp, acat);
    // Merged output projection: acat[8192,512] @ wcomb^T -> fcomb[8192,512]
    gemm64<false, true><<<dim3(8, 128), 256, 0, stream>>>(
        acat, wcomb, g_out_b, t_out_b, 256, fcomb, 512, 512);
    // Fusion MLP
    gemm64<true,  true><<<dim3(8, 128), 256, 0, stream>>>(
        fcomb, w_f1, fus_b1, fus_b1, BIG, h1, 512, 512);
    gemm64<false, false><<<dim3(4, 128), 256, 0, stream>>>(
        h1, w_f2, fus_b2, fus_b2, BIG, xf, 512, 256);
    ln_residual<<<dim3(2048), 256, 0, stream>>>(x, xf, gn_g, gn_b, x2, x2b);
    // FFN
    gemm64<true,  true><<<dim3(8, 128), 256, 0, stream>>>(
        x2b, w_n1, ffn_b1, ffn_b1, BIG, h2, 256, 512);
    gemm64<false, false><<<dim3(4, 128), 256, 0, stream>>>(
        h2, w_n2, ffn_b2, ffn_b2, BIG, xff, 512, 256);
    ln_residual<<<dim3(2048), 256, 0, stream>>>(x2, xff, fn_g, fn_b, out, nullptr);
}

// Round 8
// 252.175 us; speedup vs baseline: 1.0619x; 1.0619x over previous
//
#include <hip/hip_runtime.h>

constexpr int Bb = 4;
constexpr int Ss = 2048;
constexpr int QSTR = 1536;   // combined qkv row stride (g 0..767, t 768..1535)

typedef __bf16 bf16x8 __attribute__((ext_vector_type(8)));
typedef __bf16 bf16x4 __attribute__((ext_vector_type(4)));
typedef float  f32x4  __attribute__((ext_vector_type(4)));

// async global->LDS, 16B per lane; dest = wave-uniform base + lane*16
__device__ __forceinline__ void glds16(const void* g, void* l) {
    __builtin_amdgcn_global_load_lds(
        (const __attribute__((address_space(1))) unsigned int*)g,
        (__attribute__((address_space(3))) unsigned int*)l, 16, 0, 0);
}

// ---------------------------------------------------------------------------
// convert_all: fp32 -> bf16 for x and the 8 weight matrices, one launch.
// ---------------------------------------------------------------------------
struct CvtArgs {
    const float* src[9];
    __bf16* dst[9];
    int start[10];
};

__global__ __launch_bounds__(256) void convert_all(CvtArgs a)
{
    int e = 0;
    const int bid = blockIdx.x;
#pragma unroll
    for (int i = 0; i < 8; i++) if (bid >= a.start[i + 1]) e = i + 1;
    const int idx = (bid - a.start[e]) * 256 + threadIdx.x;
    const float* s = a.src[e];
    float4 v0 = *(const float4*)&s[(size_t)idx * 8];
    float4 v1 = *(const float4*)&s[(size_t)idx * 8 + 4];
    bf16x8 o;
    o[0] = (__bf16)v0.x; o[1] = (__bf16)v0.y; o[2] = (__bf16)v0.z; o[3] = (__bf16)v0.w;
    o[4] = (__bf16)v1.x; o[5] = (__bf16)v1.y; o[6] = (__bf16)v1.z; o[7] = (__bf16)v1.w;
    *(bf16x8*)&a.dst[e][(size_t)idx * 8] = o;
}

// ---------------------------------------------------------------------------
// gemm128: BM=BN=128, BK=64; 4 waves each 64x64 (4x4 MFMA accs). For QKV.
// XOR swizzle: LDS slot (row,g) holds global chunk (row, g^(row&7)).
// ---------------------------------------------------------------------------
__global__ __launch_bounds__(256) void gemm128(
    const __bf16* __restrict__ A, const __bf16* __restrict__ W,
    const float* __restrict__ bias, const float* __restrict__ bias2, int bsplit,
    __bf16* __restrict__ C, int K, int ldc)
{
    __shared__ __bf16 As[128 * 64];
    __shared__ __bf16 Ws[128 * 64];
    const int tid = threadIdx.x;
    const int lane = tid & 63;
    const int wv = tid >> 6;
    const int wm = (wv >> 1) * 64;
    const int wn = (wv & 1) * 64;
    const int qrow = lane & 15;
    const int quad = lane >> 4;
    const int n0 = blockIdx.x * 128;
    const int m0 = blockIdx.y * 128;

    f32x4 acc[4][4];
#pragma unroll
    for (int i = 0; i < 4; i++)
#pragma unroll
        for (int j = 0; j < 4; j++) acc[i][j] = {0.f, 0.f, 0.f, 0.f};

    for (int k0 = 0; k0 < K; k0 += 64) {
        __syncthreads();
#pragma unroll
        for (int i = 0; i < 4; i++) {
            const int c = (wv * 4 + i) * 64 + lane;
            const int row = c >> 3, g = c & 7;
            const int gs = (g ^ (row & 7)) * 8;
            glds16(&A[(size_t)(m0 + row) * K + k0 + gs], &As[(wv * 4 + i) * 512]);
            glds16(&W[(size_t)(n0 + row) * K + k0 + gs], &Ws[(wv * 4 + i) * 512]);
        }
        __syncthreads();
#pragma unroll
        for (int ksub = 0; ksub < 2; ksub++) {
            const int gl = ksub * 4 + quad;
            bf16x8 af[4], bf[4];
#pragma unroll
            for (int mi = 0; mi < 4; mi++) {
                const int row = wm + mi * 16 + qrow;
                af[mi] = *(const bf16x8*)&As[row * 64 + (gl ^ (row & 7)) * 8];
            }
#pragma unroll
            for (int ni = 0; ni < 4; ni++) {
                const int row = wn + ni * 16 + qrow;
                bf[ni] = *(const bf16x8*)&Ws[row * 64 + (gl ^ (row & 7)) * 8];
            }
#pragma unroll
            for (int mi = 0; mi < 4; mi++)
#pragma unroll
                for (int ni = 0; ni < 4; ni++)
                    acc[mi][ni] = __builtin_amdgcn_mfma_f32_16x16x32_bf16(
                        af[mi], bf[ni], acc[mi][ni], 0, 0, 0);
        }
    }

    float bz[4];
#pragma unroll
    for (int ni = 0; ni < 4; ni++) {
        const int n = n0 + wn + ni * 16 + qrow;
        bz[ni] = (n < bsplit) ? bias[n] : bias2[n - bsplit];
    }
#pragma unroll
    for (int mi = 0; mi < 4; mi++)
#pragma unroll
        for (int r = 0; r < 4; r++) {
            const int row = m0 + wm + mi * 16 + quad * 4 + r;
#pragma unroll
            for (int ni = 0; ni < 4; ni++) {
                float v = acc[mi][ni][r] + bz[ni];
                C[(size_t)row * ldc + n0 + wn + ni * 16 + qrow] = (__bf16)v;
            }
        }
}

// ---------------------------------------------------------------------------
// gemm_small: BM=32, BN=64, BK=128; 4 waves as 2(m)x2(n), each 16x32.
// 8 MFMAs/wave/iter; 24 KB LDS -> 6 blocks/CU; grids 1024-2048 blocks.
// lda decouples A row stride from K (for reading acat halves).
// ---------------------------------------------------------------------------
template<bool SILU, bool OUT_BF16>
__global__ __launch_bounds__(256) void gemm_small(
    const __bf16* __restrict__ A, const __bf16* __restrict__ W,
    const float* __restrict__ bias, void* __restrict__ C,
    int lda, int K, int ldc, int coff)
{
    __shared__ __bf16 As[32 * 128];
    __shared__ __bf16 Ws[64 * 128];
    const int tid = threadIdx.x;
    const int lane = tid & 63;
    const int wv = tid >> 6;
    const int wm = (wv >> 1) * 16;
    const int wn = (wv & 1) * 32;
    const int qrow = lane & 15;
    const int quad = lane >> 4;
    const int n0 = blockIdx.x * 64;
    const int m0 = blockIdx.y * 32;

    f32x4 acc[2];
    acc[0] = {0.f, 0.f, 0.f, 0.f};
    acc[1] = {0.f, 0.f, 0.f, 0.f};

    for (int k0 = 0; k0 < K; k0 += 128) {
        __syncthreads();
        // A: 32 rows x 16 slots = 512 chunks -> 2 glds calls/wave
#pragma unroll
        for (int i = 0; i < 2; i++) {
            const int c = (wv * 2 + i) * 64 + lane;
            const int row = c >> 4, s = c & 15;
            const int gs = ((s & 8) | ((s ^ row) & 7)) * 8;
            glds16(&A[(size_t)(m0 + row) * lda + k0 + gs], &As[(wv * 2 + i) * 512]);
        }
        // W: 64 rows x 16 slots = 1024 chunks -> 4 glds calls/wave
#pragma unroll
        for (int i = 0; i < 4; i++) {
            const int c = (wv * 4 + i) * 64 + lane;
            const int row = c >> 4, s = c & 15;
            const int gs = ((s & 8) | ((s ^ row) & 7)) * 8;
            glds16(&W[(size_t)(n0 + row) * K + k0 + gs], &Ws[(wv * 4 + i) * 512]);
        }
        __syncthreads();
#pragma unroll
        for (int ksub = 0; ksub < 4; ksub++) {
            const int gl = ksub * 4 + quad;
            bf16x8 af, bf[2];
            {
                const int row = wm + qrow;
                const int s = (gl & 8) | ((gl ^ row) & 7);
                af = *(const bf16x8*)&As[row * 128 + s * 8];
            }
#pragma unroll
            for (int ni = 0; ni < 2; ni++) {
                const int row = wn + ni * 16 + qrow;
                const int s = (gl & 8) | ((gl ^ row) & 7);
                bf[ni] = *(const bf16x8*)&Ws[row * 128 + s * 8];
            }
#pragma unroll
            for (int ni = 0; ni < 2; ni++)
                acc[ni] = __builtin_amdgcn_mfma_f32_16x16x32_bf16(
                    af, bf[ni], acc[ni], 0, 0, 0);
        }
    }

    float bz[2];
#pragma unroll
    for (int ni = 0; ni < 2; ni++) bz[ni] = bias[n0 + wn + ni * 16 + qrow];

#pragma unroll
    for (int r = 0; r < 4; r++) {
        const int row = m0 + wm + quad * 4 + r;
#pragma unroll
        for (int ni = 0; ni < 2; ni++) {
            float v = acc[ni][r] + bz[ni];
            if (SILU) v = v / (1.f + __expf(-v));
            const int col = coff + n0 + wn + ni * 16 + qrow;
            if (OUT_BF16)
                ((__bf16*)C)[(size_t)row * ldc + col] = (__bf16)v;
            else
                ((float*)C)[(size_t)row * ldc + col] = v;
        }
    }
}

// ---------------------------------------------------------------------------
// Global MHA split-K x4 partials, bf16 partial output. No-max softmax; l via
// MFMA against ones. Grid 4096 = (b:4, h:8, qc:32, sp:4); 4 waves x 16 q.
// ---------------------------------------------------------------------------
__global__ __launch_bounds__(256) void attn_global_part(
    const __bf16* __restrict__ qkv, __bf16* __restrict__ Op, float* __restrict__ Lp)
{
    __shared__ __bf16 Kl[64 * 32];
    __shared__ __bf16 Vt[32 * 72];
    __shared__ __bf16 Pl[4][16 * 72];

    const int t = threadIdx.x;
    const int bid = blockIdx.x;
    const int sp = bid & 3;
    const int qc = (bid >> 2) & 31;
    const int h  = (bid >> 7) & 7;
    const int b  = bid >> 10;
    const int bS = b * Ss;
    const int q0 = qc * 64;

    const int lane = t & 63;
    const int wv = t >> 6;
    const int qrow = lane & 15;
    const int quad = lane >> 4;
    const float cQ = 1.4426950408889634f * 0.17677669529663687f; // log2e/sqrt(32)

    bf16x8 qf;
    {
        bf16x8 qraw = *(const bf16x8*)(qkv +
            (size_t)(bS + q0 + wv * 16 + qrow) * QSTR + h * 32 + quad * 8);
#pragma unroll
        for (int i = 0; i < 8; i++) qf[i] = (__bf16)((float)qraw[i] * cQ);
    }
    bf16x8 ones;
#pragma unroll
    for (int i = 0; i < 8; i++) ones[i] = (__bf16)1.0f;

    f32x4 o0 = {0.f, 0.f, 0.f, 0.f};
    f32x4 o1 = {0.f, 0.f, 0.f, 0.f};
    f32x4 lac = {0.f, 0.f, 0.f, 0.f};
    const f32x4 z = {0.f, 0.f, 0.f, 0.f};

    const int vkey = t & 63, vdg = t >> 6;
    const int kc_c = wv * 64 + lane;
    const int kkey = kc_c >> 2, kdg = kc_c & 3;

    for (int kc = sp * 8; kc < sp * 8 + 8; kc++) {
        __syncthreads();
        glds16(qkv + (size_t)(bS + kc * 64 + kkey) * QSTR + 256 + h * 32 + kdg * 8,
               &Kl[wv * 512]);
        {
            const __bf16* src = qkv + (size_t)(bS + kc * 64 + vkey) * QSTR + 512 + h * 32 + vdg * 8;
            bf16x8 v = *(const bf16x8*)src;
#pragma unroll
            for (int i = 0; i < 8; i++) Vt[(vdg * 8 + i) * 72 + vkey] = v[i];
        }
        __syncthreads();

        f32x4 s[4];
#pragma unroll
        for (int kg = 0; kg < 4; kg++) {
            bf16x8 kf = *(const bf16x8*)&Kl[(kg * 16 + qrow) * 32 + quad * 8];
            s[kg] = __builtin_amdgcn_mfma_f32_16x16x32_bf16(qf, kf, z, 0, 0, 0);
        }
#pragma unroll
        for (int kg = 0; kg < 4; kg++) {
            float p0 = exp2f(s[kg][0]);
            float p1 = exp2f(s[kg][1]);
            float p2 = exp2f(s[kg][2]);
            float p3 = exp2f(s[kg][3]);
            __bf16* pw = &Pl[wv][kg * 16 + qrow];
            pw[(quad * 4 + 0) * 72] = (__bf16)p0;
            pw[(quad * 4 + 1) * 72] = (__bf16)p1;
            pw[(quad * 4 + 2) * 72] = (__bf16)p2;
            pw[(quad * 4 + 3) * 72] = (__bf16)p3;
        }
        bf16x8 pf0 = *(const bf16x8*)&Pl[wv][qrow * 72 + quad * 8];
        bf16x8 pf1 = *(const bf16x8*)&Pl[wv][qrow * 72 + 32 + quad * 8];
        bf16x8 vf00 = *(const bf16x8*)&Vt[qrow * 72 + quad * 8];
        bf16x8 vf01 = *(const bf16x8*)&Vt[qrow * 72 + 32 + quad * 8];
        bf16x8 vf10 = *(const bf16x8*)&Vt[(16 + qrow) * 72 + quad * 8];
        bf16x8 vf11 = *(const bf16x8*)&Vt[(16 + qrow) * 72 + 32 + quad * 8];
        o0 = __builtin_amdgcn_mfma_f32_16x16x32_bf16(pf0, vf00, o0, 0, 0, 0);
        o1 = __builtin_amdgcn_mfma_f32_16x16x32_bf16(pf0, vf10, o1, 0, 0, 0);
        lac = __builtin_amdgcn_mfma_f32_16x16x32_bf16(pf0, ones, lac, 0, 0, 0);
        o0 = __builtin_amdgcn_mfma_f32_16x16x32_bf16(pf1, vf01, o0, 0, 0, 0);
        o1 = __builtin_amdgcn_mfma_f32_16x16x32_bf16(pf1, vf11, o1, 0, 0, 0);
        lac = __builtin_amdgcn_mfma_f32_16x16x32_bf16(pf1, ones, lac, 0, 0, 0);
    }

#pragma unroll
    for (int r = 0; r < 4; r++) {
        const int row = q0 + wv * 16 + quad * 4 + r;
        const int gid = (b * 8 + h) * 2048 + row;
        __bf16* po = Op + (size_t)sp * 2097152 + (size_t)gid * 32;
        po[qrow]      = (__bf16)o0[r];
        po[16 + qrow] = (__bf16)o1[r];
        if (qrow == 0) Lp[sp * 65536 + gid] = lac[r];
    }
}

// ---------------------------------------------------------------------------
// Combine 4 bf16 split partials -> acat bf16 [B,S,512] cols 0-255.
// ---------------------------------------------------------------------------
__global__ __launch_bounds__(256) void attn_combine(
    const __bf16* __restrict__ Op, const float* __restrict__ Lp,
    __bf16* __restrict__ acat)
{
    const int t = blockIdx.x * 256 + threadIdx.x;   // 0 .. 524287
    const int gid = t >> 3;
    const int dg = t & 7;
    const int b = gid >> 14;
    const int h = (gid >> 11) & 7;
    const int q = gid & 2047;

    const float li = 1.f / (Lp[gid] + Lp[65536 + gid] + Lp[131072 + gid] + Lp[196608 + gid]);
    const __bf16* base = Op + (size_t)gid * 32 + dg * 4;
    bf16x4 a0 = *(const bf16x4*)&base[0];
    bf16x4 a1 = *(const bf16x4*)&base[2097152];
    bf16x4 a2 = *(const bf16x4*)&base[4194304];
    bf16x4 a3 = *(const bf16x4*)&base[6291456];
    bf16x4 r;
#pragma unroll
    for (int i = 0; i < 4; i++)
        r[i] = (__bf16)(((float)a0[i] + (float)a1[i] + (float)a2[i] + (float)a3[i]) * li);
    *(bf16x4*)&acat[(size_t)(b * Ss + q) * 512 + h * 32 + dg * 4] = r;
}

// ---------------------------------------------------------------------------
// Local windowed MHA -> acat cols 256-511. Wave per (b,s,h).
// ---------------------------------------------------------------------------
__global__ __launch_bounds__(256) void attn_local(
    const __bf16* __restrict__ qkv, __bf16* __restrict__ acat)
{
    const int lane = threadIdx.x & 63;
    const int w = blockIdx.x * 4 + (threadIdx.x >> 6);
    const int b = w >> 13;
    const int rem = w & 8191;
    const int s = rem >> 2;
    const int h = rem & 3;

    const float q = (float)qkv[(size_t)(b * Ss + s) * QSTR + 768 + h * 64 + lane];
    float sc[5], vv[5];
#pragma unroll
    for (int j = 0; j < 5; j++) {
        int pos = s + j - 2;
        bool valid = (pos >= 0) && (pos < Ss);
        int cpos = valid ? pos : 0;
        const size_t rb = (size_t)(b * Ss + cpos) * QSTR;
        float kj = valid ? (float)qkv[rb + 1024 + h * 64 + lane] : 0.f;
        vv[j] = valid ? (float)qkv[rb + 1280 + h * 64 + lane] : 0.f;
        float p = q * kj;
#pragma unroll
        for (int off = 32; off > 0; off >>= 1) p += __shfl_xor(p, off, 64);
        sc[j] = valid ? p * 0.125f : -1e30f;
    }
    float m = sc[0];
#pragma unroll
    for (int j = 1; j < 5; j++) m = fmaxf(m, sc[j]);
    float l = 0.f, o = 0.f;
#pragma unroll
    for (int j = 0; j < 5; j++) {
        float p = __expf(sc[j] - m);
        l += p; o += p * vv[j];
    }
    acat[(size_t)(b * Ss + s) * 512 + 256 + h * 64 + lane] = (__bf16)(o / l);
}

// ---------------------------------------------------------------------------
// out = LayerNorm(a + r) * g + be over last dim (256). Wave per token.
// ---------------------------------------------------------------------------
__global__ __launch_bounds__(256) void ln_residual(
    const float* __restrict__ a, const float* __restrict__ r,
    const float* __restrict__ g, const float* __restrict__ be,
    float* __restrict__ out, __bf16* __restrict__ ob)
{
    const int lane = threadIdx.x & 63;
    const int tok = blockIdx.x * 4 + (threadIdx.x >> 6);
    float4 xa = ((const float4*)a)[(size_t)tok * 64 + lane];
    float4 xr = ((const float4*)r)[(size_t)tok * 64 + lane];
    float4 x;
    x.x = xa.x + xr.x; x.y = xa.y + xr.y; x.z = xa.z + xr.z; x.w = xa.w + xr.w;
    float sum = x.x + x.y + x.z + x.w;
#pragma unroll
    for (int off = 32; off > 0; off >>= 1) sum += __shfl_xor(sum, off, 64);
    float mu = sum * (1.f / 256.f);
    float4 c;
    c.x = x.x - mu; c.y = x.y - mu; c.z = x.z - mu; c.w = x.w - mu;
    float sq = c.x * c.x + c.y * c.y + c.z * c.z + c.w * c.w;
#pragma unroll
    for (int off = 32; off > 0; off >>= 1) sq += __shfl_xor(sq, off, 64);
    float rs = rsqrtf(sq * (1.f / 256.f) + 1e-5f);
    float4 gg = ((const float4*)g)[lane];
    float4 bb = ((const float4*)be)[lane];
    float4 o;
    o.x = c.x * rs * gg.x + bb.x; o.y = c.y * rs * gg.y + bb.y;
    o.z = c.z * rs * gg.z + bb.z; o.w = c.w * rs * gg.w + bb.w;
    ((float4*)out)[(size_t)tok * 64 + lane] = o;
    if (ob) {
        bf16x4 hh;
        hh[0] = (__bf16)o.x; hh[1] = (__bf16)o.y; hh[2] = (__bf16)o.z; hh[3] = (__bf16)o.w;
        *(bf16x4*)&ob[(size_t)tok * 256 + lane * 4] = hh;
    }
}

// ---------------------------------------------------------------------------
extern "C" void kernel_launch(void* const* d_in, const int* in_sizes, int n_in,
                              void* d_out, int out_size, void* d_ws, size_t ws_size,
                              hipStream_t stream)
{
    const float* x      = (const float*)d_in[0];
    const float* g_in_w = (const float*)d_in[1];
    const float* g_in_b = (const float*)d_in[2];
    const float* g_out_w= (const float*)d_in[3];
    const float* g_out_b= (const float*)d_in[4];
    const float* t_in_w = (const float*)d_in[5];
    const float* t_in_b = (const float*)d_in[6];
    const float* t_out_w= (const float*)d_in[7];
    const float* t_out_b= (const float*)d_in[8];
    const float* fus_w1 = (const float*)d_in[9];
    const float* fus_b1 = (const float*)d_in[10];
    const float* fus_w2 = (const float*)d_in[11];
    const float* fus_b2 = (const float*)d_in[12];
    const float* ffn_w1 = (const float*)d_in[13];
    const float* ffn_b1 = (const float*)d_in[14];
    const float* ffn_w2 = (const float*)d_in[15];
    const float* ffn_b2 = (const float*)d_in[16];
    const float* gn_g   = (const float*)d_in[17];
    const float* gn_b   = (const float*)d_in[18];
    const float* fn_g   = (const float*)d_in[19];
    const float* fn_b   = (const float*)d_in[20];
    float* out = (float*)d_out;
    float* ws  = (float*)d_ws;

    // ws layout in f32 slots (peak 19,464,192 slots = 77.9 MB; 84 MB known-safe)
    __bf16* xb     = (__bf16*)(ws);                 // [0, 1048576)
    __bf16* wb     = (__bf16*)(ws + 1048576);       // [1048576, 1638400)
    __bf16* qkvgl  = (__bf16*)(ws + 1638400);       // [1638400, 7929856)  8192x1536
    __bf16* acat   = (__bf16*)(ws + 7929856);       // [7929856, 10027008) 8192x512
    __bf16* fcomb  = (__bf16*)(ws + 10027008);      // [10027008, 12124160) 8192x512
    __bf16* h1     = (__bf16*)(ws + 12124160);      // [12124160, 14221312) 8192x512
    float*  xf     = ws + 14221312;                 // [14221312, 16318464) fp32
    float*  x2     = ws + 16318464;                 // [16318464, 18415616) fp32
    __bf16* x2b    = (__bf16*)(ws + 18415616);      // [18415616, 19464192)
    __bf16* h2     = h1;                            // reuse
    float*  xff    = xf;                            // reuse
    // attention partials: live only between part and combine.
    // Op bf16 4x65536x32 = 4,194,304 slots overlapping fcomb+h1 (written later);
    // Lp fp32 262,144 slots overlapping x2b (written later).
    __bf16* Op = (__bf16*)(ws + 10027008);
    float*  Lp = ws + 18415616;

    __bf16* w_gin  = wb;              // [1536x256] combined (g rows 0-767, t 768-1535)
    __bf16* w_gout = wb + 393216;
    __bf16* w_tout = wb + 458752;
    __bf16* w_f1   = wb + 524288;
    __bf16* w_f2   = wb + 786432;
    __bf16* w_n1   = wb + 917504;
    __bf16* w_n2   = wb + 1048576;

    CvtArgs ca;
    ca.src[0] = x;      ca.dst[0] = xb;
    ca.src[1] = g_in_w; ca.dst[1] = w_gin;
    ca.src[2] = t_in_w; ca.dst[2] = w_gin + 196608;
    ca.src[3] = g_out_w;ca.dst[3] = w_gout;
    ca.src[4] = t_out_w;ca.dst[4] = w_tout;
    ca.src[5] = fus_w1; ca.dst[5] = w_f1;
    ca.src[6] = fus_w2; ca.dst[6] = w_f2;
    ca.src[7] = ffn_w1; ca.dst[7] = w_n1;
    ca.src[8] = ffn_w2; ca.dst[8] = w_n2;
    int st[10] = {0, 1024, 1120, 1216, 1248, 1280, 1408, 1472, 1536, 1600};
    for (int i = 0; i < 10; i++) ca.start[i] = st[i];

    convert_all<<<dim3(1600), 256, 0, stream>>>(ca);

    // Combined QKV projection: M=8192, N=1536, K=256 -> qkvgl (128x128 tiles)
    gemm128<<<dim3(12, 64), 256, 0, stream>>>(
        xb, w_gin, g_in_b, t_in_b, 768, qkvgl, 256, QSTR);
    attn_local<<<dim3(8192), 256, 0, stream>>>(qkvgl, acat);
    // Global attention: split-K x4 bf16 partials + combine -> acat cols 0-255
    attn_global_part<<<dim3(4096), 256, 0, stream>>>(qkvgl, Op, Lp);
    attn_combine<<<dim3(2048), 256, 0, stream>>>(Op, Lp, acat);
    // Output projections (separate, 1.07 GF each) into fcomb halves
    gemm_small<false, true><<<dim3(4, 256), 256, 0, stream>>>(
        acat,       w_gout, g_out_b, fcomb, 512, 256, 512, 0);
    gemm_small<false, true><<<dim3(4, 256), 256, 0, stream>>>(
        acat + 256, w_tout, t_out_b, fcomb, 512, 256, 512, 256);
    // Fusion MLP
    gemm_small<true,  true><<<dim3(8, 256), 256, 0, stream>>>(
        fcomb, w_f1, fus_b1, h1, 512, 512, 512, 0);
    gemm_small<false, false><<<dim3(4, 256), 256, 0, stream>>>(
        h1, w_f2, fus_b2, xf, 512, 512, 256, 0);
    ln_residual<<<dim3(2048), 256, 0, stream>>>(x, xf, gn_g, gn_b, x2, x2b);
    // FFN
    gemm_small<true,  true><<<dim3(8, 256), 256, 0, stream>>>(
        x2b, w_n1, ffn_b1, h2, 256, 256, 512, 0);
    gemm_small<false, false><<<dim3(4, 256), 256, 0, stream>>>(
        h2, w_n2, ffn_b2, xff, 512, 512, 256, 0);
    ln_residual<<<dim3(2048), 256, 0, stream>>>(x2, xff, fn_g, fn_b, out, nullptr);
}